// Round 1
// baseline (225.588 us; speedup 1.0000x reference)
//
#include <hip/hip_runtime.h>
#include <float.h>
#include <math.h>

// Shapes (from setup_inputs): B=4, S=2048, H=512, k_mul=64.
// Derived at launch: H = in_sizes[2]; B*S = in_sizes[0]/H; S from out_size.
// Kernels assume H == 512 (lane*8 fragmenting) and M%128==0, H%128==0, H%16==0.

#define GBM 128
#define GBN 128
#define GBK 16
#define MAXL 160   // max band length supported (k_mul+1 <= MAXL); k_mul=64 -> 65

// C[m,n] = sum_k relu(A[m,k]) * W[n,k] + bias[n]
// A: [M,K] row-major, W: [N,K] row-major (torch Linear weight layout), C: [M,N]
__global__ __launch_bounds__(256) void gemm_relu_bias(
    const float* __restrict__ A, const float* __restrict__ W,
    const float* __restrict__ bias, float* __restrict__ C,
    int M, int N, int K)
{
    __shared__ float As[GBK][GBM];
    __shared__ float Bs[GBK][GBN];
    const int tid = threadIdx.x;
    const int m0 = blockIdx.x * GBM;
    const int n0 = blockIdx.y * GBN;
    const int tx = tid & 15;
    const int ty = tid >> 4;

    float acc[2][2][4][4];
    #pragma unroll
    for (int a = 0; a < 2; ++a)
        #pragma unroll
        for (int b = 0; b < 2; ++b)
            #pragma unroll
            for (int r = 0; r < 4; ++r)
                #pragma unroll
                for (int c = 0; c < 4; ++c) acc[a][b][r][c] = 0.f;

    for (int k0 = 0; k0 < K; k0 += GBK) {
        // Stage 128x16 tiles of A (with ReLU) and W into LDS, transposed to [k][row].
        #pragma unroll
        for (int it = 0; it < 2; ++it) {
            int idx = tid + it * 256;       // float4 index 0..511
            int row = idx >> 2;             // 0..127
            int kq  = (idx & 3) << 2;       // 0,4,8,12
            float4 va = *(const float4*)(&A[(size_t)(m0 + row) * K + k0 + kq]);
            As[kq + 0][row] = fmaxf(va.x, 0.f);
            As[kq + 1][row] = fmaxf(va.y, 0.f);
            As[kq + 2][row] = fmaxf(va.z, 0.f);
            As[kq + 3][row] = fmaxf(va.w, 0.f);
            float4 vb = *(const float4*)(&W[(size_t)(n0 + row) * K + k0 + kq]);
            Bs[kq + 0][row] = vb.x;
            Bs[kq + 1][row] = vb.y;
            Bs[kq + 2][row] = vb.z;
            Bs[kq + 3][row] = vb.w;
        }
        __syncthreads();
        #pragma unroll
        for (int kk = 0; kk < GBK; ++kk) {
            float4 a0 = *(const float4*)&As[kk][ty * 4];
            float4 a1 = *(const float4*)&As[kk][ty * 4 + 64];
            float4 b0 = *(const float4*)&Bs[kk][tx * 4];
            float4 b1 = *(const float4*)&Bs[kk][tx * 4 + 64];
            float ar[2][4] = {{a0.x, a0.y, a0.z, a0.w}, {a1.x, a1.y, a1.z, a1.w}};
            float br[2][4] = {{b0.x, b0.y, b0.z, b0.w}, {b1.x, b1.y, b1.z, b1.w}};
            #pragma unroll
            for (int ah = 0; ah < 2; ++ah)
                #pragma unroll
                for (int bh = 0; bh < 2; ++bh)
                    #pragma unroll
                    for (int r = 0; r < 4; ++r)
                        #pragma unroll
                        for (int c = 0; c < 4; ++c)
                            acc[ah][bh][r][c] =
                                fmaf(ar[ah][r], br[bh][c], acc[ah][bh][r][c]);
        }
        __syncthreads();
    }

    #pragma unroll
    for (int ah = 0; ah < 2; ++ah)
        #pragma unroll
        for (int r = 0; r < 4; ++r) {
            int m = m0 + ty * 4 + ah * 64 + r;
            #pragma unroll
            for (int bh = 0; bh < 2; ++bh) {
                int n = n0 + tx * 4 + bh * 64;
                float4 v;
                v.x = acc[ah][bh][r][0] + bias[n + 0];
                v.y = acc[ah][bh][r][1] + bias[n + 1];
                v.z = acc[ah][bh][r][2] + bias[n + 2];
                v.w = acc[ah][bh][r][3] + bias[n + 3];
                *(float4*)(&C[(size_t)m * N + n]) = v;
            }
        }
}

// One block per (query row i, batch b). 256 threads = 4 waves.
// scores over band [j0, i] -> softmax -> write full attn row (zeros outside
// band) -> out[b,i,:] = sum_j p_j * k[b,j,:].
__global__ __launch_bounds__(256) void band_attn(
    const float* __restrict__ q, const float* __restrict__ k,
    const int* __restrict__ kmul_p,
    float* __restrict__ out, float* __restrict__ attn,
    int S, int H, float scale)
{
    const int i = blockIdx.x;
    const int b = blockIdx.y;
    const int tid = threadIdx.x;
    const int wave = tid >> 6;
    const int lane = tid & 63;

    __shared__ float sc[MAXL];
    __shared__ float red[8];

    const int km = kmul_p[0];
    const int j0 = max(i - km, 0);
    const int L = i - j0 + 1;   // <= km+1 <= MAXL

    // Per-lane q fragment: 8 contiguous floats (H == 512 = 64 lanes * 8).
    const float* qrow = &q[((size_t)b * S + i) * H];
    const int h0 = lane * 8;
    float4 qa = *(const float4*)&qrow[h0];
    float4 qb = *(const float4*)&qrow[h0 + 4];

    // Each wave handles band positions j = wave, wave+4, ...
    for (int j = wave; j < L; j += 4) {
        const float* kr = &k[((size_t)b * S + j0 + j) * H + h0];
        float4 ka = *(const float4*)&kr[0];
        float4 kb = *(const float4*)&kr[4];
        float d = qa.x * ka.x + qa.y * ka.y + qa.z * ka.z + qa.w * ka.w
                + qb.x * kb.x + qb.y * kb.y + qb.z * kb.z + qb.w * kb.w;
        #pragma unroll
        for (int off = 32; off; off >>= 1) d += __shfl_xor(d, off, 64);
        if (lane == 0) sc[j] = d * scale;
    }
    __syncthreads();

    // Block softmax over sc[0..L)
    float v = (tid < L) ? sc[tid] : -FLT_MAX;
    float m = v;
    #pragma unroll
    for (int off = 32; off; off >>= 1) m = fmaxf(m, __shfl_xor(m, off, 64));
    if (lane == 0) red[wave] = m;
    __syncthreads();
    m = fmaxf(fmaxf(red[0], red[1]), fmaxf(red[2], red[3]));
    float e = (tid < L) ? __expf(v - m) : 0.f;
    float s = e;
    #pragma unroll
    for (int off = 32; off; off >>= 1) s += __shfl_xor(s, off, 64);
    if (lane == 0) red[4 + wave] = s;
    if (tid < L) sc[tid] = e;
    __syncthreads();
    const float inv = 1.f / (red[4] + red[5] + red[6] + red[7]);

    // Full attn row write (zeros outside band) — one coalesced pass.
    float* arow = &attn[((size_t)b * S + i) * S];
    for (int jj = tid; jj < S; jj += 256) {
        int d2 = jj - j0;
        float val = (d2 >= 0 && jj <= i) ? sc[d2] * inv : 0.f;
        arow[jj] = val;
    }

    // out[b,i,h] = sum_j p_j * k[b, j0+j, h]; thread owns h = tid, tid+256.
    float acc0 = 0.f, acc1 = 0.f;
    for (int j = 0; j < L; ++j) {
        float p = sc[j] * inv;
        const float* kr = &k[((size_t)b * S + j0 + j) * H];
        acc0 = fmaf(p, kr[tid], acc0);
        acc1 = fmaf(p, kr[tid + 256], acc1);
    }
    float* orow = &out[((size_t)b * S + i) * H];
    orow[tid] = acc0;
    orow[tid + 256] = acc1;
}

extern "C" void kernel_launch(void* const* d_in, const int* in_sizes, int n_in,
                              void* d_out, int out_size, void* d_ws, size_t ws_size,
                              hipStream_t stream)
{
    const float* x  = (const float*)d_in[0];
    const float* Wk = (const float*)d_in[1];
    const float* bk = (const float*)d_in[2];
    const float* Wq = (const float*)d_in[3];
    const float* bq = (const float*)d_in[4];
    const int*   km = (const int*)d_in[5];

    const int H = in_sizes[2];                               // 512
    const long long BS = (long long)in_sizes[0] / H;         // B*S = 8192
    const long long S = ((long long)out_size - (long long)in_sizes[0]) / BS; // 2048
    const int B = (int)(BS / S);

    // Workspace: q then k, each BS*H floats (16.8 MB each).
    float* qbuf = (float*)d_ws;
    float* kbuf = qbuf + (size_t)BS * H;

    dim3 gg((unsigned)((BS + GBM - 1) / GBM), (unsigned)((H + GBN - 1) / GBN));
    gemm_relu_bias<<<gg, 256, 0, stream>>>(x, Wq, bq, qbuf, (int)BS, H, H);
    gemm_relu_bias<<<gg, 256, 0, stream>>>(x, Wk, bk, kbuf, (int)BS, H, H);

    float* outp  = (float*)d_out;
    float* attnp = outp + (size_t)BS * H;
    const float scale = 1.0f / sqrtf((float)H);

    dim3 ag((unsigned)S, (unsigned)B);
    band_attn<<<ag, 256, 0, stream>>>(qbuf, kbuf, km, outp, attnp,
                                      (int)S, H, scale);
}

// Round 2
// 120.395 us; speedup vs baseline: 1.8737x; 1.8737x over previous
//
#include <hip/hip_runtime.h>
#include <hip/hip_bf16.h>
#include <float.h>
#include <math.h>

// Shapes: B=4, S=2048, H=512, k_mul=64. M=B*S=8192.
// GEMM: C[m,n] = relu(A)[m,:] . W[n,:] + bias[n]  (torch Linear, B^T layout)
// MFMA bf16 path: inputs rounded to bf16 (RNE), fp32 accumulate.

typedef __attribute__((ext_vector_type(4))) float f32x4;
typedef __attribute__((ext_vector_type(8))) short short8;   // 8 bf16 = 4 VGPRs
typedef __attribute__((ext_vector_type(4))) short short4v;  // 4 bf16 = 8 bytes

#define TM 128
#define TN 128
#define TK 64
#define MAXL 160   // band length bound (k_mul+1 <= MAXL)

static __device__ __forceinline__ short f2bf(float f) {
    __hip_bfloat16 h = __float2bfloat16(f);  // RNE
    return *reinterpret_cast<short*>(&h);
}

// 128x128 tile, 4 waves (2x2), each wave 64x64 = 4x4 MFMA frags of 16x16x32.
// LDS tiles stored [row][64] bf16 with XOR swizzle (short idx ^= (row&7)<<3)
// so fragment ds_read_b128 (16 lanes, 16 rows, same col) is 2-way (free).
__global__ __launch_bounds__(256) void gemm_mfma_relu_bias(
    const float* __restrict__ A,
    const float* __restrict__ Wq, const float* __restrict__ bq, float* __restrict__ Cq,
    const float* __restrict__ Wk, const float* __restrict__ bk, float* __restrict__ Ck,
    int M, int N, int K)
{
    const float* W    = blockIdx.z ? Wk : Wq;
    const float* bias = blockIdx.z ? bk : bq;
    float*       C    = blockIdx.z ? Ck : Cq;

    __shared__ __align__(16) short As[TM * TK];
    __shared__ __align__(16) short Bs[TN * TK];

    const int tid  = threadIdx.x;
    const int lane = tid & 63;
    const int wave = tid >> 6;
    const int wr   = (wave >> 1) * 64;   // wave row offset in tile
    const int wc   = (wave & 1) * 64;    // wave col offset in tile
    const int m0   = blockIdx.x * TM;
    const int n0   = blockIdx.y * TN;

    const int lr = lane & 15;            // fragment row (A) / col-row (B)
    const int lk = (lane >> 4) * 8;      // k-offset within K=32 step

    f32x4 acc[4][4];
    #pragma unroll
    for (int m = 0; m < 4; ++m)
        #pragma unroll
        for (int n = 0; n < 4; ++n)
            #pragma unroll
            for (int r = 0; r < 4; ++r) acc[m][n][r] = 0.f;

    for (int k0 = 0; k0 < K; k0 += TK) {
        // Stage: 128x64 f32 of A (relu) and W -> bf16 LDS, swizzled.
        #pragma unroll
        for (int i = 0; i < 8; ++i) {
            int f   = tid + (i << 8);        // float4 index 0..2047
            int row = f >> 4;                // 16 float4 per 64-col row
            int cq  = (f & 15) << 2;         // float col 0..60
            int sidx = row * TK + (cq ^ ((row & 7) << 3));
            float4 va = *(const float4*)&A[(size_t)(m0 + row) * K + k0 + cq];
            short4v sa;
            sa.x = f2bf(fmaxf(va.x, 0.f));
            sa.y = f2bf(fmaxf(va.y, 0.f));
            sa.z = f2bf(fmaxf(va.z, 0.f));
            sa.w = f2bf(fmaxf(va.w, 0.f));
            *(short4v*)&As[sidx] = sa;
            float4 vb = *(const float4*)&W[(size_t)(n0 + row) * K + k0 + cq];
            short4v sb;
            sb.x = f2bf(vb.x);
            sb.y = f2bf(vb.y);
            sb.z = f2bf(vb.z);
            sb.w = f2bf(vb.w);
            *(short4v*)&Bs[sidx] = sb;
        }
        __syncthreads();

        #pragma unroll
        for (int kk = 0; kk < 2; ++kk) {
            short8 af[4], bf[4];
            #pragma unroll
            for (int m = 0; m < 4; ++m) {
                int r = wr + m * 16 + lr;
                af[m] = *(const short8*)&As[r * TK + ((kk * 32 + lk) ^ ((r & 7) << 3))];
            }
            #pragma unroll
            for (int n = 0; n < 4; ++n) {
                int r = wc + n * 16 + lr;
                bf[n] = *(const short8*)&Bs[r * TK + ((kk * 32 + lk) ^ ((r & 7) << 3))];
            }
            #pragma unroll
            for (int m = 0; m < 4; ++m)
                #pragma unroll
                for (int n = 0; n < 4; ++n)
                    acc[m][n] = __builtin_amdgcn_mfma_f32_16x16x32_bf16(
                        af[m], bf[n], acc[m][n], 0, 0, 0);
        }
        __syncthreads();
    }

    // Epilogue: C/D layout col=lane&15, row=(lane>>4)*4+reg (verified m89/m91).
    const int cr = (lane >> 4) * 4;
    #pragma unroll
    for (int m = 0; m < 4; ++m) {
        #pragma unroll
        for (int n = 0; n < 4; ++n) {
            int col = n0 + wc + n * 16 + lr;
            float bv = bias[col];
            #pragma unroll
            for (int r = 0; r < 4; ++r) {
                int row = m0 + wr + m * 16 + cr + r;
                C[(size_t)row * N + col] = acc[m][n][r] + bv;
            }
        }
    }
}

// One block per (query row i, batch b). 256 threads = 4 waves.
__global__ __launch_bounds__(256) void band_attn(
    const float* __restrict__ q, const float* __restrict__ k,
    const int* __restrict__ kmul_p,
    float* __restrict__ out, float* __restrict__ attn,
    int S, int H, float scale)
{
    const int i = blockIdx.x;
    const int b = blockIdx.y;
    const int tid = threadIdx.x;
    const int wave = tid >> 6;
    const int lane = tid & 63;

    __shared__ float sc[MAXL];
    __shared__ float red[8];

    const int km = kmul_p[0];
    const int j0 = max(i - km, 0);
    const int L = i - j0 + 1;   // <= km+1 <= MAXL

    const float* qrow = &q[((size_t)b * S + i) * H];
    const int h0 = lane * 8;
    float4 qa = *(const float4*)&qrow[h0];
    float4 qb = *(const float4*)&qrow[h0 + 4];

    for (int j = wave; j < L; j += 4) {
        const float* kr = &k[((size_t)b * S + j0 + j) * H + h0];
        float4 ka = *(const float4*)&kr[0];
        float4 kb = *(const float4*)&kr[4];
        float d = qa.x * ka.x + qa.y * ka.y + qa.z * ka.z + qa.w * ka.w
                + qb.x * kb.x + qb.y * kb.y + qb.z * kb.z + qb.w * kb.w;
        #pragma unroll
        for (int off = 32; off; off >>= 1) d += __shfl_xor(d, off, 64);
        if (lane == 0) sc[j] = d * scale;
    }
    __syncthreads();

    float v = (tid < L) ? sc[tid] : -FLT_MAX;
    float m = v;
    #pragma unroll
    for (int off = 32; off; off >>= 1) m = fmaxf(m, __shfl_xor(m, off, 64));
    if (lane == 0) red[wave] = m;
    __syncthreads();
    m = fmaxf(fmaxf(red[0], red[1]), fmaxf(red[2], red[3]));
    float e = (tid < L) ? __expf(v - m) : 0.f;
    float s = e;
    #pragma unroll
    for (int off = 32; off; off >>= 1) s += __shfl_xor(s, off, 64);
    if (lane == 0) red[4 + wave] = s;
    if (tid < L) sc[tid] = e;
    __syncthreads();
    const float inv = 1.f / (red[4] + red[5] + red[6] + red[7]);

    float* arow = &attn[((size_t)b * S + i) * S];
    for (int jj = tid; jj < S; jj += 256) {
        int d2 = jj - j0;
        float val = (d2 >= 0 && jj <= i) ? sc[d2] * inv : 0.f;
        arow[jj] = val;
    }

    float acc0 = 0.f, acc1 = 0.f;
    for (int j = 0; j < L; ++j) {
        float p = sc[j] * inv;
        const float* kr = &k[((size_t)b * S + j0 + j) * H];
        acc0 = fmaf(p, kr[tid], acc0);
        acc1 = fmaf(p, kr[tid + 256], acc1);
    }
    float* orow = &out[((size_t)b * S + i) * H];
    orow[tid] = acc0;
    orow[tid + 256] = acc1;
}

extern "C" void kernel_launch(void* const* d_in, const int* in_sizes, int n_in,
                              void* d_out, int out_size, void* d_ws, size_t ws_size,
                              hipStream_t stream)
{
    const float* x  = (const float*)d_in[0];
    const float* Wk = (const float*)d_in[1];
    const float* bk = (const float*)d_in[2];
    const float* Wq = (const float*)d_in[3];
    const float* bq = (const float*)d_in[4];
    const int*   km = (const int*)d_in[5];

    const int H = in_sizes[2];                               // 512
    const long long BS = (long long)in_sizes[0] / H;         // B*S = 8192
    const long long S = ((long long)out_size - (long long)in_sizes[0]) / BS; // 2048
    const int B = (int)(BS / S);

    float* qbuf = (float*)d_ws;
    float* kbuf = qbuf + (size_t)BS * H;

    dim3 gg((unsigned)(BS / TM), (unsigned)(H / TN), 2);
    gemm_mfma_relu_bias<<<gg, 256, 0, stream>>>(x, Wq, bq, qbuf, Wk, bk, kbuf,
                                                (int)BS, H, H);

    float* outp  = (float*)d_out;
    float* attnp = outp + (size_t)BS * H;
    const float scale = 1.0f / sqrtf((float)H);

    dim3 ag((unsigned)S, (unsigned)B);
    band_attn<<<ag, 256, 0, stream>>>(qbuf, kbuf, km, outp, attnp,
                                      (int)S, H, scale);
}

// Round 4
// 58.459 us; speedup vs baseline: 3.8589x; 2.0595x over previous
//
#include <hip/hip_runtime.h>
#include <hip/hip_bf16.h>
#include <float.h>
#include <math.h>

// B=4, S=2048, H=512, k_mul=64. M=B*S=8192.
// Stage 1: GEMM q/k = relu(x)@W^T + b via bf16 MFMA, emitting bf16 qbf/kbf
//          (row-major [m][h]) and kT (per-batch [h][s]) for the PV step.
// Stage 2: banded attention, 32 query rows/block, 128-key padded window,
//          MFMA scores (direct-from-global frags), f32 softmax in LDS,
//          MFMA PV from kT. attn written densely (zeros outside window).

typedef __attribute__((ext_vector_type(4))) float f32x4;
typedef __attribute__((ext_vector_type(8))) float f32x8;
typedef __attribute__((ext_vector_type(8))) short short8;
typedef __attribute__((ext_vector_type(4))) short short4v;

#define TM 128
#define TN 128
#define TK 64

#define QBLK 32
#define KW 128     // padded key window; requires k_mul <= 96
#define SCP 132    // f32 LDS row stride (pad)
#define PPAD 136   // bf16 LDS row stride (272B = 17*16B, keeps b128 align)

static __device__ __forceinline__ short f2bf(float f) {
    __hip_bfloat16 h = __float2bfloat16(f);  // RNE
    return *reinterpret_cast<short*>(&h);
}

// ---------------- GEMM: C = relu(A) @ W^T + bias, bf16 outputs ----------------
__global__ __launch_bounds__(256) void gemm_mfma_relu_bias_bf16(
    const float* __restrict__ A,
    const float* __restrict__ Wq, const float* __restrict__ bq, short* __restrict__ Cq,
    const float* __restrict__ Wk, const float* __restrict__ bk, short* __restrict__ Ck,
    short* __restrict__ CkT,
    int M, int N, int K, int S)
{
    const float* W    = blockIdx.z ? Wk : Wq;
    const float* bias = blockIdx.z ? bk : bq;
    short*       C    = blockIdx.z ? Ck : Cq;

    __shared__ __align__(16) short lds[TM * TN];   // 32KB; union: staging + epilogue
    short* As = lds;               // [128][64] swizzled
    short* Bs = lds + TM * TK;

    const int tid  = threadIdx.x;
    const int lane = tid & 63;
    const int wave = tid >> 6;
    const int wr   = (wave >> 1) * 64;
    const int wc   = (wave & 1) * 64;
    const int m0   = blockIdx.x * TM;
    const int n0   = blockIdx.y * TN;

    const int lr = lane & 15;
    const int lk = (lane >> 4) * 8;

    f32x4 acc[4][4];
    #pragma unroll
    for (int m = 0; m < 4; ++m)
        #pragma unroll
        for (int n = 0; n < 4; ++n)
            #pragma unroll
            for (int r = 0; r < 4; ++r) acc[m][n][r] = 0.f;

    for (int k0 = 0; k0 < K; k0 += TK) {
        #pragma unroll
        for (int i = 0; i < 8; ++i) {
            int f   = tid + (i << 8);
            int row = f >> 4;
            int cq  = (f & 15) << 2;
            int sidx = row * TK + (cq ^ ((row & 7) << 3));
            float4 va = *(const float4*)&A[(size_t)(m0 + row) * K + k0 + cq];
            short4v sa;
            sa.x = f2bf(fmaxf(va.x, 0.f));
            sa.y = f2bf(fmaxf(va.y, 0.f));
            sa.z = f2bf(fmaxf(va.z, 0.f));
            sa.w = f2bf(fmaxf(va.w, 0.f));
            *(short4v*)&As[sidx] = sa;
            float4 vb = *(const float4*)&W[(size_t)(n0 + row) * K + k0 + cq];
            short4v sb;
            sb.x = f2bf(vb.x);
            sb.y = f2bf(vb.y);
            sb.z = f2bf(vb.z);
            sb.w = f2bf(vb.w);
            *(short4v*)&Bs[sidx] = sb;
        }
        __syncthreads();

        #pragma unroll
        for (int kk = 0; kk < 2; ++kk) {
            short8 af[4], bf[4];
            #pragma unroll
            for (int m = 0; m < 4; ++m) {
                int r = wr + m * 16 + lr;
                af[m] = *(const short8*)&As[r * TK + ((kk * 32 + lk) ^ ((r & 7) << 3))];
            }
            #pragma unroll
            for (int n = 0; n < 4; ++n) {
                int r = wc + n * 16 + lr;
                bf[n] = *(const short8*)&Bs[r * TK + ((kk * 32 + lk) ^ ((r & 7) << 3))];
            }
            #pragma unroll
            for (int m = 0; m < 4; ++m)
                #pragma unroll
                for (int n = 0; n < 4; ++n)
                    acc[m][n] = __builtin_amdgcn_mfma_f32_16x16x32_bf16(
                        af[m], bf[n], acc[m][n], 0, 0, 0);
        }
        __syncthreads();
    }

    // ---- epilogue: bias add, bf16, LDS-roundtrip for coalesced writes ----
    float bv[4];
    #pragma unroll
    for (int n = 0; n < 4; ++n) bv[n] = bias[n0 + wc + n * 16 + lr];
    const int cr = (lane >> 4) * 4;

    // pass 1: row-major [m][n] (swizzled), then coalesced C write
    #pragma unroll
    for (int m = 0; m < 4; ++m)
        #pragma unroll
        for (int n = 0; n < 4; ++n) {
            int col = wc + n * 16 + lr;
            #pragma unroll
            for (int r = 0; r < 4; ++r) {
                int row = wr + m * 16 + cr + r;
                lds[row * TN + (col ^ ((row & 7) << 3))] = f2bf(acc[m][n][r] + bv[n]);
            }
        }
    __syncthreads();
    #pragma unroll
    for (int i = 0; i < 8; ++i) {
        int idx = tid + (i << 8);
        int m = idx >> 4, n8 = (idx & 15) << 3;
        short8 v = *(const short8*)&lds[m * TN + (n8 ^ ((m & 7) << 3))];
        *(short8*)&C[(size_t)(m0 + m) * N + n0 + n8] = v;
    }

    if (blockIdx.z) {   // K: also emit kT[b][h][s]
        __syncthreads();
        #pragma unroll
        for (int m = 0; m < 4; ++m)
            #pragma unroll
            for (int n = 0; n < 4; ++n) {
                int col = wc + n * 16 + lr;
                #pragma unroll
                for (int r = 0; r < 4; ++r) {
                    int row = wr + m * 16 + cr + r;
                    lds[col * TM + (row ^ ((col & 7) << 3))] = f2bf(acc[m][n][r] + bv[n]);
                }
            }
        __syncthreads();
        #pragma unroll
        for (int i = 0; i < 8; ++i) {
            int idx = tid + (i << 8);
            int n = idx >> 4, m8 = (idx & 15) << 3;
            short8 v = *(const short8*)&lds[n * TM + (m8 ^ ((n & 7) << 3))];
            int gm = m0 + m8;
            int gb = gm / S, s = gm % S;
            *(short8*)&CkT[((size_t)gb * N + (n0 + n)) * (size_t)S + s] = v;
        }
    }
}

// ---------------- banded attention ----------------
// grid (S/QBLK, B), 256 threads = 4 waves. Wave w: score keys [32w,32w+32),
// PV h-slice [128w, 128w+128).
__global__ __launch_bounds__(256) void band_attn_mfma(
    const short* __restrict__ qbf, const short* __restrict__ kbf,
    const short* __restrict__ kT, const int* __restrict__ kmul_p,
    float* __restrict__ out, float* __restrict__ attn,
    int S, int H, float scale)
{
    __shared__ float sc[QBLK][SCP];   // scores -> normalized probs (f32)
    __shared__ short pl[QBLK][PPAD];  // probs bf16 for PV A-frags

    const int i0  = blockIdx.x * QBLK;
    const int b   = blockIdx.y;
    const int tid = threadIdx.x;
    const int lane = tid & 63;
    const int w    = tid >> 6;
    const int km   = kmul_p[0];
    const int jbase = max(i0 - km, 0);

    const int lr = lane & 15;
    const int lk = (lane >> 4) * 8;
    const int fr = (lane >> 4) * 4;   // frag row base = (lane>>4)*4 + reg

    // ---- scores: D[q][key], keys w*32 .. w*32+31 ----
    f32x4 sacc[2][2];
    #pragma unroll
    for (int m = 0; m < 2; ++m)
        #pragma unroll
        for (int n = 0; n < 2; ++n)
            #pragma unroll
            for (int r = 0; r < 4; ++r) sacc[m][n][r] = 0.f;

    const short* qb = qbf + ((size_t)b * S + i0) * H;
    const short* kb = kbf + ((size_t)b * S + jbase) * H;
    #pragma unroll
    for (int ks = 0; ks < 16; ++ks) {      // H=512 / 32
        int hoff = ks * 32 + lk;
        short8 qa0 = *(const short8*)(qb + (size_t)lr * H + hoff);
        short8 qa1 = *(const short8*)(qb + (size_t)(lr + 16) * H + hoff);
        short8 kf0 = *(const short8*)(kb + (size_t)(w * 32 + lr) * H + hoff);
        short8 kf1 = *(const short8*)(kb + (size_t)(w * 32 + 16 + lr) * H + hoff);
        sacc[0][0] = __builtin_amdgcn_mfma_f32_16x16x32_bf16(qa0, kf0, sacc[0][0], 0, 0, 0);
        sacc[0][1] = __builtin_amdgcn_mfma_f32_16x16x32_bf16(qa0, kf1, sacc[0][1], 0, 0, 0);
        sacc[1][0] = __builtin_amdgcn_mfma_f32_16x16x32_bf16(qa1, kf0, sacc[1][0], 0, 0, 0);
        sacc[1][1] = __builtin_amdgcn_mfma_f32_16x16x32_bf16(qa1, kf1, sacc[1][1], 0, 0, 0);
    }

    // mask + scale -> sc
    #pragma unroll
    for (int m = 0; m < 2; ++m)
        #pragma unroll
        for (int n = 0; n < 2; ++n) {
            int key = w * 32 + n * 16 + lr;
            int kg  = jbase + key;
            #pragma unroll
            for (int r = 0; r < 4; ++r) {
                int q = m * 16 + fr + r;
                int irow = i0 + q;
                bool ok = (kg <= irow) && (kg + km >= irow);
                sc[q][key] = ok ? sacc[m][n][r] * scale : -1e30f;
            }
        }
    __syncthreads();

    // ---- softmax: 8 threads per row ----
    {
        int r  = tid >> 3;
        int t8 = tid & 7;
        float4 v[4];
        #pragma unroll
        for (int j = 0; j < 4; ++j)
            v[j] = *(const float4*)&sc[r][t8 * 16 + j * 4];
        float mx = -FLT_MAX;
        #pragma unroll
        for (int j = 0; j < 4; ++j)
            mx = fmaxf(mx, fmaxf(fmaxf(v[j].x, v[j].y), fmaxf(v[j].z, v[j].w)));
        mx = fmaxf(mx, __shfl_xor(mx, 1, 64));
        mx = fmaxf(mx, __shfl_xor(mx, 2, 64));
        mx = fmaxf(mx, __shfl_xor(mx, 4, 64));
        float e[16], s = 0.f;
        #pragma unroll
        for (int j = 0; j < 4; ++j) {
            e[j*4+0] = __expf(v[j].x - mx);
            e[j*4+1] = __expf(v[j].y - mx);
            e[j*4+2] = __expf(v[j].z - mx);
            e[j*4+3] = __expf(v[j].w - mx);
            s += e[j*4+0] + e[j*4+1] + e[j*4+2] + e[j*4+3];
        }
        s += __shfl_xor(s, 1, 64);
        s += __shfl_xor(s, 2, 64);
        s += __shfl_xor(s, 4, 64);
        float inv = __frcp_rn(s);
        #pragma unroll
        for (int j = 0; j < 4; ++j) {
            float4 p;
            p.x = e[j*4+0] * inv; p.y = e[j*4+1] * inv;
            p.z = e[j*4+2] * inv; p.w = e[j*4+3] * inv;
            *(float4*)&sc[r][t8 * 16 + j * 4] = p;
            short4v pb;
            pb.x = f2bf(p.x); pb.y = f2bf(p.y);
            pb.z = f2bf(p.z); pb.w = f2bf(p.w);
            *(short4v*)&pl[r][t8 * 16 + j * 4] = pb;
        }
    }
    __syncthreads();

    // ---- dense attn write: band probs, zeros elsewhere ----
    // FIX(r3): single 8-wide named vector — previous version wrote through
    // (float*)&o0 past its end (UB) leaving the second float4 uninitialized.
    float* abase = attn + ((size_t)b * S + i0) * (size_t)S;
    const int col = tid * 8;   // 32B-aligned, covers the S=2048 row exactly
    #pragma unroll 4
    for (int r = 0; r < QBLK; ++r) {
        f32x8 o;
        #pragma unroll
        for (int j = 0; j < 8; ++j) {
            int rel = col + j - jbase;
            o[j] = ((unsigned)rel < (unsigned)KW) ? sc[r][rel] : 0.f;
        }
        *(f32x8*)(abase + (size_t)r * S + col) = o;
    }

    // ---- PV: out[q][h] = P @ K, B-frags direct from kT[b][h][s] ----
    short8 pa[2][4];
    #pragma unroll
    for (int m = 0; m < 2; ++m)
        #pragma unroll
        for (int ks = 0; ks < 4; ++ks)
            pa[m][ks] = *(const short8*)&pl[m * 16 + lr][ks * 32 + lk];

    const short* ktb = kT + (size_t)b * H * S;
    float* obase = out + ((size_t)b * S + i0) * H;
    #pragma unroll
    for (int nf = 0; nf < 8; ++nf) {
        int h = w * 128 + nf * 16 + lr;
        f32x4 oacc[2];
        #pragma unroll
        for (int r = 0; r < 4; ++r) { oacc[0][r] = 0.f; oacc[1][r] = 0.f; }
        #pragma unroll
        for (int ks = 0; ks < 4; ++ks) {
            short8 kf = *(const short8*)(ktb + (size_t)h * S + jbase + ks * 32 + lk);
            oacc[0] = __builtin_amdgcn_mfma_f32_16x16x32_bf16(pa[0][ks], kf, oacc[0], 0, 0, 0);
            oacc[1] = __builtin_amdgcn_mfma_f32_16x16x32_bf16(pa[1][ks], kf, oacc[1], 0, 0, 0);
        }
        #pragma unroll
        for (int m = 0; m < 2; ++m)
            #pragma unroll
            for (int r = 0; r < 4; ++r) {
                int q = m * 16 + fr + r;
                obase[(size_t)q * H + h] = oacc[m][r];
            }
    }
}

extern "C" void kernel_launch(void* const* d_in, const int* in_sizes, int n_in,
                              void* d_out, int out_size, void* d_ws, size_t ws_size,
                              hipStream_t stream)
{
    const float* x  = (const float*)d_in[0];
    const float* Wk = (const float*)d_in[1];
    const float* bk = (const float*)d_in[2];
    const float* Wq = (const float*)d_in[3];
    const float* bq = (const float*)d_in[4];
    const int*   km = (const int*)d_in[5];

    const int H = in_sizes[2];                               // 512
    const long long BS = (long long)in_sizes[0] / H;         // 8192
    const long long S = ((long long)out_size - (long long)in_sizes[0]) / BS; // 2048
    const int B = (int)(BS / S);

    // ws layout: kT first (so its tail overruns into qbf: finite bf16),
    // then qbf, then kbf (kbf tail overruns into untouched/poisoned ws).
    short* kT  = (short*)d_ws;                  // [B][H][S]
    short* qbf = kT + (size_t)B * H * S;        // [BS][H]
    short* kbf = qbf + (size_t)BS * H;          // [BS][H]

    dim3 gg((unsigned)(BS / TM), (unsigned)(H / TN), 2);
    gemm_mfma_relu_bias_bf16<<<gg, 256, 0, stream>>>(
        x, Wq, bq, qbf, Wk, bk, kbf, kT, (int)BS, H, H, (int)S);

    float* outp  = (float*)d_out;
    float* attnp = outp + (size_t)BS * H;
    const float scale = 1.0f / sqrtf((float)H);

    dim3 ag((unsigned)(S / QBLK), (unsigned)B);
    band_attn_mfma<<<ag, 256, 0, stream>>>(qbf, kbf, kT, km, outp, attnp,
                                           (int)S, H, scale);
}

// Round 5
// 58.230 us; speedup vs baseline: 3.8741x; 1.0039x over previous
//
#include <hip/hip_runtime.h>
#include <hip/hip_bf16.h>
#include <float.h>
#include <math.h>

// B=4, S=2048, H=512, k_mul=64. M=B*S=8192.
// Stage 1: GEMM q/k = relu(x)@W^T + b via bf16 MFMA, emitting bf16 qbf/kbf
//          (row-major [m][h]) and kT (per-batch [h][s]) for the PV step.
// Stage 2: banded attention, 32 query rows/block, 128-key padded window,
//          8 waves (512 thr): wave w scores keys [16w,16w+16), PV h-slice
//          [64w,64w+64). MFMA scores direct-from-global, f32 softmax in LDS,
//          MFMA PV from kT. attn written densely (zeros outside window).

typedef __attribute__((ext_vector_type(4))) float f32x4;
typedef __attribute__((ext_vector_type(8))) short short8;
typedef __attribute__((ext_vector_type(4))) short short4v;

#define TM 128
#define TN 128
#define TK 64

#define QBLK 32
#define KW 128     // padded key window; requires k_mul <= 96
#define SCP 132    // f32 LDS row stride (pad)
#define PPAD 136   // bf16 LDS row stride (272B, keeps b128 align, odd/16 stride)

static __device__ __forceinline__ short f2bf(float f) {
    __hip_bfloat16 h = __float2bfloat16(f);  // RNE
    return *reinterpret_cast<short*>(&h);
}

// ---------------- GEMM: C = relu(A) @ W^T + bias, bf16 outputs ----------------
// (unchanged from round 4 — passed at absmax 0.0156)
__global__ __launch_bounds__(256) void gemm_mfma_relu_bias_bf16(
    const float* __restrict__ A,
    const float* __restrict__ Wq, const float* __restrict__ bq, short* __restrict__ Cq,
    const float* __restrict__ Wk, const float* __restrict__ bk, short* __restrict__ Ck,
    short* __restrict__ CkT,
    int M, int N, int K, int S)
{
    const float* W    = blockIdx.z ? Wk : Wq;
    const float* bias = blockIdx.z ? bk : bq;
    short*       C    = blockIdx.z ? Ck : Cq;

    __shared__ __align__(16) short lds[TM * TN];   // 32KB; union: staging + epilogue
    short* As = lds;               // [128][64] swizzled
    short* Bs = lds + TM * TK;

    const int tid  = threadIdx.x;
    const int lane = tid & 63;
    const int wave = tid >> 6;
    const int wr   = (wave >> 1) * 64;
    const int wc   = (wave & 1) * 64;
    const int m0   = blockIdx.x * TM;
    const int n0   = blockIdx.y * TN;

    const int lr = lane & 15;
    const int lk = (lane >> 4) * 8;

    f32x4 acc[4][4];
    #pragma unroll
    for (int m = 0; m < 4; ++m)
        #pragma unroll
        for (int n = 0; n < 4; ++n)
            #pragma unroll
            for (int r = 0; r < 4; ++r) acc[m][n][r] = 0.f;

    for (int k0 = 0; k0 < K; k0 += TK) {
        #pragma unroll
        for (int i = 0; i < 8; ++i) {
            int f   = tid + (i << 8);
            int row = f >> 4;
            int cq  = (f & 15) << 2;
            int sidx = row * TK + (cq ^ ((row & 7) << 3));
            float4 va = *(const float4*)&A[(size_t)(m0 + row) * K + k0 + cq];
            short4v sa;
            sa.x = f2bf(fmaxf(va.x, 0.f));
            sa.y = f2bf(fmaxf(va.y, 0.f));
            sa.z = f2bf(fmaxf(va.z, 0.f));
            sa.w = f2bf(fmaxf(va.w, 0.f));
            *(short4v*)&As[sidx] = sa;
            float4 vb = *(const float4*)&W[(size_t)(n0 + row) * K + k0 + cq];
            short4v sb;
            sb.x = f2bf(vb.x);
            sb.y = f2bf(vb.y);
            sb.z = f2bf(vb.z);
            sb.w = f2bf(vb.w);
            *(short4v*)&Bs[sidx] = sb;
        }
        __syncthreads();

        #pragma unroll
        for (int kk = 0; kk < 2; ++kk) {
            short8 af[4], bf[4];
            #pragma unroll
            for (int m = 0; m < 4; ++m) {
                int r = wr + m * 16 + lr;
                af[m] = *(const short8*)&As[r * TK + ((kk * 32 + lk) ^ ((r & 7) << 3))];
            }
            #pragma unroll
            for (int n = 0; n < 4; ++n) {
                int r = wc + n * 16 + lr;
                bf[n] = *(const short8*)&Bs[r * TK + ((kk * 32 + lk) ^ ((r & 7) << 3))];
            }
            #pragma unroll
            for (int m = 0; m < 4; ++m)
                #pragma unroll
                for (int n = 0; n < 4; ++n)
                    acc[m][n] = __builtin_amdgcn_mfma_f32_16x16x32_bf16(
                        af[m], bf[n], acc[m][n], 0, 0, 0);
        }
        __syncthreads();
    }

    // ---- epilogue: bias add, bf16, LDS-roundtrip for coalesced writes ----
    float bv[4];
    #pragma unroll
    for (int n = 0; n < 4; ++n) bv[n] = bias[n0 + wc + n * 16 + lr];
    const int cr = (lane >> 4) * 4;

    #pragma unroll
    for (int m = 0; m < 4; ++m)
        #pragma unroll
        for (int n = 0; n < 4; ++n) {
            int col = wc + n * 16 + lr;
            #pragma unroll
            for (int r = 0; r < 4; ++r) {
                int row = wr + m * 16 + cr + r;
                lds[row * TN + (col ^ ((row & 7) << 3))] = f2bf(acc[m][n][r] + bv[n]);
            }
        }
    __syncthreads();
    #pragma unroll
    for (int i = 0; i < 8; ++i) {
        int idx = tid + (i << 8);
        int m = idx >> 4, n8 = (idx & 15) << 3;
        short8 v = *(const short8*)&lds[m * TN + (n8 ^ ((m & 7) << 3))];
        *(short8*)&C[(size_t)(m0 + m) * N + n0 + n8] = v;
    }

    if (blockIdx.z) {   // K: also emit kT[b][h][s]
        __syncthreads();
        #pragma unroll
        for (int m = 0; m < 4; ++m)
            #pragma unroll
            for (int n = 0; n < 4; ++n) {
                int col = wc + n * 16 + lr;
                #pragma unroll
                for (int r = 0; r < 4; ++r) {
                    int row = wr + m * 16 + cr + r;
                    lds[col * TM + (row ^ ((col & 7) << 3))] = f2bf(acc[m][n][r] + bv[n]);
                }
            }
        __syncthreads();
        #pragma unroll
        for (int i = 0; i < 8; ++i) {
            int idx = tid + (i << 8);
            int n = idx >> 4, m8 = (idx & 15) << 3;
            short8 v = *(const short8*)&lds[n * TM + (m8 ^ ((n & 7) << 3))];
            int gm = m0 + m8;
            int gb = gm / S, s = gm % S;
            *(short8*)&CkT[((size_t)gb * N + (n0 + n)) * (size_t)S + s] = v;
        }
    }
}

// ---------------- banded attention (8 waves / 512 threads) ----------------
// grid (S/QBLK, B). Wave w: score keys [16w,16w+16), PV h-slice [64w,64w+64).
__global__ __launch_bounds__(512) void band_attn_mfma(
    const short* __restrict__ qbf, const short* __restrict__ kbf,
    const short* __restrict__ kT, const int* __restrict__ kmul_p,
    float* __restrict__ out, float* __restrict__ attn,
    int S, int H, float scale)
{
    __shared__ float sc[QBLK][SCP];   // scores -> normalized probs (f32)
    __shared__ short pl[QBLK][PPAD];  // probs bf16 for PV A-frags

    const int i0  = blockIdx.x * QBLK;
    const int b   = blockIdx.y;
    const int tid = threadIdx.x;
    const int lane = tid & 63;
    const int w    = tid >> 6;
    const int km   = kmul_p[0];
    const int jbase = max(i0 - km, 0);

    const int lr = lane & 15;
    const int lk = (lane >> 4) * 8;
    const int fr = (lane >> 4) * 4;   // frag row base = (lane>>4)*4 + reg

    // ---- scores: D[q][key], this wave's keys = [16w, 16w+16) ----
    f32x4 sacc[2];
    #pragma unroll
    for (int m = 0; m < 2; ++m)
        #pragma unroll
        for (int r = 0; r < 4; ++r) sacc[m][r] = 0.f;

    const short* qb = qbf + ((size_t)b * S + i0) * H;
    const short* kb = kbf + ((size_t)b * S + jbase) * H;
    #pragma unroll
    for (int ks = 0; ks < 16; ++ks) {      // H=512 / 32
        int hoff = ks * 32 + lk;
        short8 qa0 = *(const short8*)(qb + (size_t)lr * H + hoff);
        short8 qa1 = *(const short8*)(qb + (size_t)(lr + 16) * H + hoff);
        short8 kf  = *(const short8*)(kb + (size_t)(w * 16 + lr) * H + hoff);
        sacc[0] = __builtin_amdgcn_mfma_f32_16x16x32_bf16(qa0, kf, sacc[0], 0, 0, 0);
        sacc[1] = __builtin_amdgcn_mfma_f32_16x16x32_bf16(qa1, kf, sacc[1], 0, 0, 0);
    }

    // mask + scale -> sc. key col of D = lane&15 -> key = 16w + lr.
    {
        int key = w * 16 + lr;
        int kg  = jbase + key;
        #pragma unroll
        for (int m = 0; m < 2; ++m)
            #pragma unroll
            for (int r = 0; r < 4; ++r) {
                int q = m * 16 + fr + r;
                int irow = i0 + q;
                bool ok = (kg <= irow) && (kg + km >= irow);
                sc[q][key] = ok ? sacc[m][r] * scale : -1e30f;
            }
    }
    __syncthreads();

    // ---- softmax: 16 threads per row, 8 cols each ----
    {
        int r  = tid >> 4;        // 0..31
        int t  = tid & 15;
        float4 v[2];
        #pragma unroll
        for (int j = 0; j < 2; ++j)
            v[j] = *(const float4*)&sc[r][t * 8 + j * 4];
        float mx = -FLT_MAX;
        #pragma unroll
        for (int j = 0; j < 2; ++j)
            mx = fmaxf(mx, fmaxf(fmaxf(v[j].x, v[j].y), fmaxf(v[j].z, v[j].w)));
        mx = fmaxf(mx, __shfl_xor(mx, 1, 64));
        mx = fmaxf(mx, __shfl_xor(mx, 2, 64));
        mx = fmaxf(mx, __shfl_xor(mx, 4, 64));
        mx = fmaxf(mx, __shfl_xor(mx, 8, 64));
        float e[8], s = 0.f;
        #pragma unroll
        for (int j = 0; j < 2; ++j) {
            e[j*4+0] = __expf(v[j].x - mx);
            e[j*4+1] = __expf(v[j].y - mx);
            e[j*4+2] = __expf(v[j].z - mx);
            e[j*4+3] = __expf(v[j].w - mx);
            s += e[j*4+0] + e[j*4+1] + e[j*4+2] + e[j*4+3];
        }
        s += __shfl_xor(s, 1, 64);
        s += __shfl_xor(s, 2, 64);
        s += __shfl_xor(s, 4, 64);
        s += __shfl_xor(s, 8, 64);
        float inv = __frcp_rn(s);
        #pragma unroll
        for (int j = 0; j < 2; ++j) {
            float4 p;
            p.x = e[j*4+0] * inv; p.y = e[j*4+1] * inv;
            p.z = e[j*4+2] * inv; p.w = e[j*4+3] * inv;
            *(float4*)&sc[r][t * 8 + j * 4] = p;
            short4v pb;
            pb.x = f2bf(p.x); pb.y = f2bf(p.y);
            pb.z = f2bf(p.z); pb.w = f2bf(p.w);
            *(short4v*)&pl[r][t * 8 + j * 4] = pb;
        }
    }
    __syncthreads();

    // ---- dense attn write: band probs, zeros elsewhere (f32x4/thread) ----
    float* abase = attn + ((size_t)b * S + i0) * (size_t)S;
    const int col = tid * 4;   // 512 threads * 4 = 2048 = S exactly
    #pragma unroll 4
    for (int r = 0; r < QBLK; ++r) {
        f32x4 o;
        #pragma unroll
        for (int j = 0; j < 4; ++j) {
            int rel = col + j - jbase;
            o[j] = ((unsigned)rel < (unsigned)KW) ? sc[r][rel] : 0.f;
        }
        *(f32x4*)(abase + (size_t)r * S + col) = o;
    }

    // ---- PV: out[q][h] = P @ K, B-frags direct from kT[b][h][s] ----
    short8 pa[2][4];
    #pragma unroll
    for (int m = 0; m < 2; ++m)
        #pragma unroll
        for (int ks = 0; ks < 4; ++ks)
            pa[m][ks] = *(const short8*)&pl[m * 16 + lr][ks * 32 + lk];

    const short* ktb = kT + (size_t)b * H * S;
    float* obase = out + ((size_t)b * S + i0) * H;
    #pragma unroll
    for (int nf = 0; nf < 4; ++nf) {
        int h = w * 64 + nf * 16 + lr;
        f32x4 oacc[2];
        #pragma unroll
        for (int r = 0; r < 4; ++r) { oacc[0][r] = 0.f; oacc[1][r] = 0.f; }
        #pragma unroll
        for (int ks = 0; ks < 4; ++ks) {
            short8 kf = *(const short8*)(ktb + (size_t)h * S + jbase + ks * 32 + lk);
            oacc[0] = __builtin_amdgcn_mfma_f32_16x16x32_bf16(pa[0][ks], kf, oacc[0], 0, 0, 0);
            oacc[1] = __builtin_amdgcn_mfma_f32_16x16x32_bf16(pa[1][ks], kf, oacc[1], 0, 0, 0);
        }
        #pragma unroll
        for (int m = 0; m < 2; ++m)
            #pragma unroll
            for (int r = 0; r < 4; ++r) {
                int q = m * 16 + fr + r;
                obase[(size_t)q * H + h] = oacc[m][r];
            }
    }
}

extern "C" void kernel_launch(void* const* d_in, const int* in_sizes, int n_in,
                              void* d_out, int out_size, void* d_ws, size_t ws_size,
                              hipStream_t stream)
{
    const float* x  = (const float*)d_in[0];
    const float* Wk = (const float*)d_in[1];
    const float* bk = (const float*)d_in[2];
    const float* Wq = (const float*)d_in[3];
    const float* bq = (const float*)d_in[4];
    const int*   km = (const int*)d_in[5];

    const int H = in_sizes[2];                               // 512
    const long long BS = (long long)in_sizes[0] / H;         // 8192
    const long long S = ((long long)out_size - (long long)in_sizes[0]) / BS; // 2048
    const int B = (int)(BS / S);

    // ws layout: kT first (so attn-kernel tail reads overrun into qbf: finite
    // bf16), then qbf, then kbf (kbf tail overruns into untouched ws).
    short* kT  = (short*)d_ws;                  // [B][H][S]
    short* qbf = kT + (size_t)B * H * S;        // [BS][H]
    short* kbf = qbf + (size_t)BS * H;          // [BS][H]

    dim3 gg((unsigned)(BS / TM), (unsigned)(H / TN), 2);
    gemm_mfma_relu_bias_bf16<<<gg, 256, 0, stream>>>(
        x, Wq, bq, qbf, Wk, bk, kbf, kT, (int)BS, H, H, (int)S);

    float* outp  = (float*)d_out;
    float* attnp = outp + (size_t)BS * H;
    const float scale = 1.0f / sqrtf((float)H);

    dim3 ag((unsigned)(S / QBLK), (unsigned)B);
    band_attn_mfma<<<ag, 512, 0, stream>>>(qbf, kbf, kT, km, outp, attnp,
                                           (int)S, H, scale);
}

// Round 6
// 56.850 us; speedup vs baseline: 3.9681x; 1.0243x over previous
//
#include <hip/hip_runtime.h>
#include <hip/hip_bf16.h>
#include <float.h>
#include <math.h>

// B=4, S=2048, H=512, k_mul=64. M=B*S=8192.
// Stage 1: GEMM q/k = relu(x)@W^T + b via bf16 MFMA -> bf16 qbf/kbf + kT.
// Stage 2: banded attention, QBLK=32 rows/block, 128-key padded window,
//          8 waves; XCD-contiguous tile swizzle (adjacent q-tiles share 75%
//          of their key window -> keep them on one XCD's L2); nontemporal
//          stores for attn/out (never re-read; avoid L2 pollution).

typedef __attribute__((ext_vector_type(4))) float f32x4;
typedef __attribute__((ext_vector_type(8))) short short8;
typedef __attribute__((ext_vector_type(4))) short short4v;

#define TM 128
#define TN 128
#define TK 64

#define QBLK 32
#define KW 128     // padded key window; requires k_mul <= 96
#define SCP 132    // f32 LDS row stride (pad)
#define PPAD 136   // bf16 LDS row stride

static __device__ __forceinline__ short f2bf(float f) {
    __hip_bfloat16 h = __float2bfloat16(f);  // RNE
    return *reinterpret_cast<short*>(&h);
}

// ---------------- GEMM: C = relu(A) @ W^T + bias, bf16 outputs ----------------
__global__ __launch_bounds__(256) void gemm_mfma_relu_bias_bf16(
    const float* __restrict__ A,
    const float* __restrict__ Wq, const float* __restrict__ bq, short* __restrict__ Cq,
    const float* __restrict__ Wk, const float* __restrict__ bk, short* __restrict__ Ck,
    short* __restrict__ CkT,
    int M, int N, int K, int sshift)
{
    const float* W    = blockIdx.z ? Wk : Wq;
    const float* bias = blockIdx.z ? bk : bq;
    short*       C    = blockIdx.z ? Ck : Cq;

    __shared__ __align__(16) short lds[TM * TN];   // 32KB; union: staging + epilogue
    short* As = lds;               // [128][64] swizzled
    short* Bs = lds + TM * TK;

    const int tid  = threadIdx.x;
    const int lane = tid & 63;
    const int wave = tid >> 6;
    const int wr   = (wave >> 1) * 64;
    const int wc   = (wave & 1) * 64;
    const int m0   = blockIdx.x * TM;
    const int n0   = blockIdx.y * TN;

    const int lr = lane & 15;
    const int lk = (lane >> 4) * 8;

    f32x4 acc[4][4];
    #pragma unroll
    for (int m = 0; m < 4; ++m)
        #pragma unroll
        for (int n = 0; n < 4; ++n)
            #pragma unroll
            for (int r = 0; r < 4; ++r) acc[m][n][r] = 0.f;

    for (int k0 = 0; k0 < K; k0 += TK) {
        #pragma unroll
        for (int i = 0; i < 8; ++i) {
            int f   = tid + (i << 8);
            int row = f >> 4;
            int cq  = (f & 15) << 2;
            int sidx = row * TK + (cq ^ ((row & 7) << 3));
            float4 va = *(const float4*)&A[(size_t)(m0 + row) * K + k0 + cq];
            short4v sa;
            sa.x = f2bf(fmaxf(va.x, 0.f));
            sa.y = f2bf(fmaxf(va.y, 0.f));
            sa.z = f2bf(fmaxf(va.z, 0.f));
            sa.w = f2bf(fmaxf(va.w, 0.f));
            *(short4v*)&As[sidx] = sa;
            float4 vb = *(const float4*)&W[(size_t)(n0 + row) * K + k0 + cq];
            short4v sb;
            sb.x = f2bf(vb.x);
            sb.y = f2bf(vb.y);
            sb.z = f2bf(vb.z);
            sb.w = f2bf(vb.w);
            *(short4v*)&Bs[sidx] = sb;
        }
        __syncthreads();

        #pragma unroll
        for (int kk = 0; kk < 2; ++kk) {
            short8 af[4], bf[4];
            #pragma unroll
            for (int m = 0; m < 4; ++m) {
                int r = wr + m * 16 + lr;
                af[m] = *(const short8*)&As[r * TK + ((kk * 32 + lk) ^ ((r & 7) << 3))];
            }
            #pragma unroll
            for (int n = 0; n < 4; ++n) {
                int r = wc + n * 16 + lr;
                bf[n] = *(const short8*)&Bs[r * TK + ((kk * 32 + lk) ^ ((r & 7) << 3))];
            }
            #pragma unroll
            for (int m = 0; m < 4; ++m)
                #pragma unroll
                for (int n = 0; n < 4; ++n)
                    acc[m][n] = __builtin_amdgcn_mfma_f32_16x16x32_bf16(
                        af[m], bf[n], acc[m][n], 0, 0, 0);
        }
        __syncthreads();
    }

    // ---- epilogue: bias add, bf16, LDS-roundtrip for coalesced writes ----
    float bv[4];
    #pragma unroll
    for (int n = 0; n < 4; ++n) bv[n] = bias[n0 + wc + n * 16 + lr];
    const int cr = (lane >> 4) * 4;

    #pragma unroll
    for (int m = 0; m < 4; ++m)
        #pragma unroll
        for (int n = 0; n < 4; ++n) {
            int col = wc + n * 16 + lr;
            #pragma unroll
            for (int r = 0; r < 4; ++r) {
                int row = wr + m * 16 + cr + r;
                lds[row * TN + (col ^ ((row & 7) << 3))] = f2bf(acc[m][n][r] + bv[n]);
            }
        }
    __syncthreads();
    #pragma unroll
    for (int i = 0; i < 8; ++i) {
        int idx = tid + (i << 8);
        int m = idx >> 4, n8 = (idx & 15) << 3;
        short8 v = *(const short8*)&lds[m * TN + (n8 ^ ((m & 7) << 3))];
        *(short8*)&C[(size_t)(m0 + m) * N + n0 + n8] = v;
    }

    if (blockIdx.z) {   // K: also emit kT[b][h][s]
        __syncthreads();
        #pragma unroll
        for (int m = 0; m < 4; ++m)
            #pragma unroll
            for (int n = 0; n < 4; ++n) {
                int col = wc + n * 16 + lr;
                #pragma unroll
                for (int r = 0; r < 4; ++r) {
                    int row = wr + m * 16 + cr + r;
                    lds[col * TM + (row ^ ((col & 7) << 3))] = f2bf(acc[m][n][r] + bv[n]);
                }
            }
        __syncthreads();
        const int smask = (1 << sshift) - 1;
        #pragma unroll
        for (int i = 0; i < 8; ++i) {
            int idx = tid + (i << 8);
            int n = idx >> 4, m8 = (idx & 15) << 3;
            short8 v = *(const short8*)&lds[n * TM + (m8 ^ ((n & 7) << 3))];
            int gm = m0 + m8;
            int gb = gm >> sshift, s = gm & smask;
            *(short8*)&CkT[((size_t)gb * N + (n0 + n)) * (size_t)(smask + 1) + s] = v;
        }
    }
}

// ---------------- banded attention (8 waves / 512 threads) ----------------
// grid (S/QBLK, B). Wave w: score keys [16w,16w+16), PV h-slice [64w,64w+64).
__global__ __launch_bounds__(512) void band_attn_mfma(
    const short* __restrict__ qbf, const short* __restrict__ kbf,
    const short* __restrict__ kT, const int* __restrict__ kmul_p,
    float* __restrict__ out, float* __restrict__ attn,
    int S, int H, float scale)
{
    __shared__ float sc[QBLK][SCP];   // scores -> normalized probs (f32)
    __shared__ short pl[QBLK][PPAD];  // probs bf16 for PV A-frags

    // XCD-contiguous tile swizzle: physical blocks {c, c+8, c+16, ...} run on
    // XCD c (dispatch id % 8; gridDim.x*by contributes 0 mod 8). Give them
    // ADJACENT q-tiles so the shared 75% of the key window stays in that
    // XCD's L2. Bijective when gridDim.x % 8 == 0.
    int bx = blockIdx.x;
    int tile = bx;
    if ((gridDim.x & 7) == 0) {
        int chunk = gridDim.x >> 3;
        tile = (bx & 7) * chunk + (bx >> 3);
    }

    const int i0  = tile * QBLK;
    const int b   = blockIdx.y;
    const int tid = threadIdx.x;
    const int lane = tid & 63;
    const int w    = tid >> 6;
    const int km   = kmul_p[0];
    const int jbase = max(i0 - km, 0);

    const int lr = lane & 15;
    const int lk = (lane >> 4) * 8;
    const int fr = (lane >> 4) * 4;   // frag row base = (lane>>4)*4 + reg

    // ---- scores: D[q][key], this wave's keys = [16w, 16w+16) ----
    f32x4 sacc[2];
    #pragma unroll
    for (int m = 0; m < 2; ++m)
        #pragma unroll
        for (int r = 0; r < 4; ++r) sacc[m][r] = 0.f;

    const short* qb = qbf + ((size_t)b * S + i0) * H;
    const short* kb = kbf + ((size_t)b * S + jbase) * H;
    #pragma unroll
    for (int ks = 0; ks < 16; ++ks) {      // H=512 / 32
        int hoff = ks * 32 + lk;
        short8 qa0 = *(const short8*)(qb + (size_t)lr * H + hoff);
        short8 qa1 = *(const short8*)(qb + (size_t)(lr + 16) * H + hoff);
        short8 kf  = *(const short8*)(kb + (size_t)(w * 16 + lr) * H + hoff);
        sacc[0] = __builtin_amdgcn_mfma_f32_16x16x32_bf16(qa0, kf, sacc[0], 0, 0, 0);
        sacc[1] = __builtin_amdgcn_mfma_f32_16x16x32_bf16(qa1, kf, sacc[1], 0, 0, 0);
    }

    // mask + scale -> sc. key col of D = lane&15 -> key = 16w + lr.
    {
        int key = w * 16 + lr;
        int kg  = jbase + key;
        #pragma unroll
        for (int m = 0; m < 2; ++m)
            #pragma unroll
            for (int r = 0; r < 4; ++r) {
                int q = m * 16 + fr + r;
                int irow = i0 + q;
                bool ok = (kg <= irow) && (kg + km >= irow);
                sc[q][key] = ok ? sacc[m][r] * scale : -1e30f;
            }
    }
    __syncthreads();

    // ---- softmax: 16 threads per row, 8 cols each ----
    {
        int r  = tid >> 4;        // 0..31
        int t  = tid & 15;
        float4 v[2];
        #pragma unroll
        for (int j = 0; j < 2; ++j)
            v[j] = *(const float4*)&sc[r][t * 8 + j * 4];
        float mx = -FLT_MAX;
        #pragma unroll
        for (int j = 0; j < 2; ++j)
            mx = fmaxf(mx, fmaxf(fmaxf(v[j].x, v[j].y), fmaxf(v[j].z, v[j].w)));
        mx = fmaxf(mx, __shfl_xor(mx, 1, 64));
        mx = fmaxf(mx, __shfl_xor(mx, 2, 64));
        mx = fmaxf(mx, __shfl_xor(mx, 4, 64));
        mx = fmaxf(mx, __shfl_xor(mx, 8, 64));
        float e[8], s = 0.f;
        #pragma unroll
        for (int j = 0; j < 2; ++j) {
            e[j*4+0] = __expf(v[j].x - mx);
            e[j*4+1] = __expf(v[j].y - mx);
            e[j*4+2] = __expf(v[j].z - mx);
            e[j*4+3] = __expf(v[j].w - mx);
            s += e[j*4+0] + e[j*4+1] + e[j*4+2] + e[j*4+3];
        }
        s += __shfl_xor(s, 1, 64);
        s += __shfl_xor(s, 2, 64);
        s += __shfl_xor(s, 4, 64);
        s += __shfl_xor(s, 8, 64);
        float inv = __frcp_rn(s);
        #pragma unroll
        for (int j = 0; j < 2; ++j) {
            float4 p;
            p.x = e[j*4+0] * inv; p.y = e[j*4+1] * inv;
            p.z = e[j*4+2] * inv; p.w = e[j*4+3] * inv;
            *(float4*)&sc[r][t * 8 + j * 4] = p;
            short4v pb;
            pb.x = f2bf(p.x); pb.y = f2bf(p.y);
            pb.z = f2bf(p.z); pb.w = f2bf(p.w);
            *(short4v*)&pl[r][t * 8 + j * 4] = pb;
        }
    }
    __syncthreads();

    // ---- dense attn write: band probs, zeros elsewhere (nontemporal) ----
    float* abase = attn + ((size_t)b * S + i0) * (size_t)S;
    const int col = tid * 4;   // 512 threads * 4 = 2048 = S exactly
    #pragma unroll 4
    for (int r = 0; r < QBLK; ++r) {
        f32x4 o;
        #pragma unroll
        for (int j = 0; j < 4; ++j) {
            int rel = col + j - jbase;
            o[j] = ((unsigned)rel < (unsigned)KW) ? sc[r][rel] : 0.f;
        }
        __builtin_nontemporal_store(o, (f32x4*)(abase + (size_t)r * S + col));
    }

    // ---- PV: out[q][h] = P @ K, B-frags direct from kT[b][h][s] ----
    short8 pa[2][4];
    #pragma unroll
    for (int m = 0; m < 2; ++m)
        #pragma unroll
        for (int ks = 0; ks < 4; ++ks)
            pa[m][ks] = *(const short8*)&pl[m * 16 + lr][ks * 32 + lk];

    const short* ktb = kT + (size_t)b * H * S;
    float* obase = out + ((size_t)b * S + i0) * H;
    #pragma unroll
    for (int nf = 0; nf < 4; ++nf) {
        int h = w * 64 + nf * 16 + lr;
        f32x4 oacc[2];
        #pragma unroll
        for (int r = 0; r < 4; ++r) { oacc[0][r] = 0.f; oacc[1][r] = 0.f; }
        #pragma unroll
        for (int ks = 0; ks < 4; ++ks) {
            short8 kf = *(const short8*)(ktb + (size_t)h * S + jbase + ks * 32 + lk);
            oacc[0] = __builtin_amdgcn_mfma_f32_16x16x32_bf16(pa[0][ks], kf, oacc[0], 0, 0, 0);
            oacc[1] = __builtin_amdgcn_mfma_f32_16x16x32_bf16(pa[1][ks], kf, oacc[1], 0, 0, 0);
        }
        #pragma unroll
        for (int m = 0; m < 2; ++m)
            #pragma unroll
            for (int r = 0; r < 4; ++r) {
                int q = m * 16 + fr + r;
                __builtin_nontemporal_store(oacc[m][r], obase + (size_t)q * H + h);
            }
    }
}

extern "C" void kernel_launch(void* const* d_in, const int* in_sizes, int n_in,
                              void* d_out, int out_size, void* d_ws, size_t ws_size,
                              hipStream_t stream)
{
    const float* x  = (const float*)d_in[0];
    const float* Wk = (const float*)d_in[1];
    const float* bk = (const float*)d_in[2];
    const float* Wq = (const float*)d_in[3];
    const float* bq = (const float*)d_in[4];
    const int*   km = (const int*)d_in[5];

    const int H = in_sizes[2];                               // 512
    const long long BS = (long long)in_sizes[0] / H;         // 8192
    const long long S = ((long long)out_size - (long long)in_sizes[0]) / BS; // 2048
    const int B = (int)(BS / S);
    int sshift = 0;
    while ((1LL << sshift) < S) ++sshift;                    // S is a power of 2

    // ws layout: kT first (tail reads overrun into qbf: finite bf16),
    // then qbf, then kbf.
    short* kT  = (short*)d_ws;                  // [B][H][S]
    short* qbf = kT + (size_t)B * H * S;        // [BS][H]
    short* kbf = qbf + (size_t)BS * H;          // [BS][H]

    dim3 gg((unsigned)(BS / TM), (unsigned)(H / TN), 2);
    gemm_mfma_relu_bias_bf16<<<gg, 256, 0, stream>>>(
        x, Wq, bq, qbf, Wk, bk, kbf, kT, (int)BS, H, H, sshift);

    float* outp  = (float*)d_out;
    float* attnp = outp + (size_t)BS * H;
    const float scale = 1.0f / sqrtf((float)H);

    dim3 ag((unsigned)(S / QBLK), (unsigned)B);
    band_attn_mfma<<<ag, 512, 0, stream>>>(qbf, kbf, kT, km, outp, attnp,
                                           (int)S, H, scale);
}

// Round 7
// 56.191 us; speedup vs baseline: 4.0147x; 1.0117x over previous
//
#include <hip/hip_runtime.h>
#include <hip/hip_bf16.h>
#include <float.h>
#include <math.h>

// B=4, S=2048, H=512, k_mul=64. M=B*S=8192.
// Stage 1: GEMM q/k = relu(x)@W^T + b via bf16 MFMA -> bf16 qbf/kbf + kT.
// Stage 2: banded attention, QBLK=16 rows/block (512 blocks = 2 blocks/CU so
//          one block's compute overlaps another's store drain), KW=96 window,
//          8 waves: waves 0-5 score 16 keys each, all 8 do PV (64 h each).
//          Phase order: scores -> softmax -> PV(loads+MFMA) -> out stores ->
//          attn stores LAST (vmcnt is a single in-order counter; putting the
//          67MB store burst after all loads keeps PV off the drain path).

typedef __attribute__((ext_vector_type(4))) float f32x4;
typedef __attribute__((ext_vector_type(8))) short short8;
typedef __attribute__((ext_vector_type(4))) short short4v;

#define TM 128
#define TN 128
#define TK 64

#define QBLK 16
#define KW 96      // window; needs k_mul <= KW - QBLK = 80
#define SCP 100    // f32 LDS row stride (pad)
#define PPAD 104   // bf16 LDS row stride

static __device__ __forceinline__ short f2bf(float f) {
    __hip_bfloat16 h = __float2bfloat16(f);  // RNE
    return *reinterpret_cast<short*>(&h);
}

// ---------------- GEMM: C = relu(A) @ W^T + bias, bf16 outputs ----------------
// (unchanged from round 6)
__global__ __launch_bounds__(256) void gemm_mfma_relu_bias_bf16(
    const float* __restrict__ A,
    const float* __restrict__ Wq, const float* __restrict__ bq, short* __restrict__ Cq,
    const float* __restrict__ Wk, const float* __restrict__ bk, short* __restrict__ Ck,
    short* __restrict__ CkT,
    int M, int N, int K, int sshift)
{
    const float* W    = blockIdx.z ? Wk : Wq;
    const float* bias = blockIdx.z ? bk : bq;
    short*       C    = blockIdx.z ? Ck : Cq;

    __shared__ __align__(16) short lds[TM * TN];   // 32KB; union: staging + epilogue
    short* As = lds;               // [128][64] swizzled
    short* Bs = lds + TM * TK;

    const int tid  = threadIdx.x;
    const int lane = tid & 63;
    const int wave = tid >> 6;
    const int wr   = (wave >> 1) * 64;
    const int wc   = (wave & 1) * 64;
    const int m0   = blockIdx.x * TM;
    const int n0   = blockIdx.y * TN;

    const int lr = lane & 15;
    const int lk = (lane >> 4) * 8;

    f32x4 acc[4][4];
    #pragma unroll
    for (int m = 0; m < 4; ++m)
        #pragma unroll
        for (int n = 0; n < 4; ++n)
            #pragma unroll
            for (int r = 0; r < 4; ++r) acc[m][n][r] = 0.f;

    for (int k0 = 0; k0 < K; k0 += TK) {
        #pragma unroll
        for (int i = 0; i < 8; ++i) {
            int f   = tid + (i << 8);
            int row = f >> 4;
            int cq  = (f & 15) << 2;
            int sidx = row * TK + (cq ^ ((row & 7) << 3));
            float4 va = *(const float4*)&A[(size_t)(m0 + row) * K + k0 + cq];
            short4v sa;
            sa.x = f2bf(fmaxf(va.x, 0.f));
            sa.y = f2bf(fmaxf(va.y, 0.f));
            sa.z = f2bf(fmaxf(va.z, 0.f));
            sa.w = f2bf(fmaxf(va.w, 0.f));
            *(short4v*)&As[sidx] = sa;
            float4 vb = *(const float4*)&W[(size_t)(n0 + row) * K + k0 + cq];
            short4v sb;
            sb.x = f2bf(vb.x);
            sb.y = f2bf(vb.y);
            sb.z = f2bf(vb.z);
            sb.w = f2bf(vb.w);
            *(short4v*)&Bs[sidx] = sb;
        }
        __syncthreads();

        #pragma unroll
        for (int kk = 0; kk < 2; ++kk) {
            short8 af[4], bf[4];
            #pragma unroll
            for (int m = 0; m < 4; ++m) {
                int r = wr + m * 16 + lr;
                af[m] = *(const short8*)&As[r * TK + ((kk * 32 + lk) ^ ((r & 7) << 3))];
            }
            #pragma unroll
            for (int n = 0; n < 4; ++n) {
                int r = wc + n * 16 + lr;
                bf[n] = *(const short8*)&Bs[r * TK + ((kk * 32 + lk) ^ ((r & 7) << 3))];
            }
            #pragma unroll
            for (int m = 0; m < 4; ++m)
                #pragma unroll
                for (int n = 0; n < 4; ++n)
                    acc[m][n] = __builtin_amdgcn_mfma_f32_16x16x32_bf16(
                        af[m], bf[n], acc[m][n], 0, 0, 0);
        }
        __syncthreads();
    }

    // ---- epilogue: bias add, bf16, LDS-roundtrip for coalesced writes ----
    float bv[4];
    #pragma unroll
    for (int n = 0; n < 4; ++n) bv[n] = bias[n0 + wc + n * 16 + lr];
    const int cr = (lane >> 4) * 4;

    #pragma unroll
    for (int m = 0; m < 4; ++m)
        #pragma unroll
        for (int n = 0; n < 4; ++n) {
            int col = wc + n * 16 + lr;
            #pragma unroll
            for (int r = 0; r < 4; ++r) {
                int row = wr + m * 16 + cr + r;
                lds[row * TN + (col ^ ((row & 7) << 3))] = f2bf(acc[m][n][r] + bv[n]);
            }
        }
    __syncthreads();
    #pragma unroll
    for (int i = 0; i < 8; ++i) {
        int idx = tid + (i << 8);
        int m = idx >> 4, n8 = (idx & 15) << 3;
        short8 v = *(const short8*)&lds[m * TN + (n8 ^ ((m & 7) << 3))];
        *(short8*)&C[(size_t)(m0 + m) * N + n0 + n8] = v;
    }

    if (blockIdx.z) {   // K: also emit kT[b][h][s]
        __syncthreads();
        #pragma unroll
        for (int m = 0; m < 4; ++m)
            #pragma unroll
            for (int n = 0; n < 4; ++n) {
                int col = wc + n * 16 + lr;
                #pragma unroll
                for (int r = 0; r < 4; ++r) {
                    int row = wr + m * 16 + cr + r;
                    lds[col * TM + (row ^ ((col & 7) << 3))] = f2bf(acc[m][n][r] + bv[n]);
                }
            }
        __syncthreads();
        const int smask = (1 << sshift) - 1;
        #pragma unroll
        for (int i = 0; i < 8; ++i) {
            int idx = tid + (i << 8);
            int n = idx >> 4, m8 = (idx & 15) << 3;
            short8 v = *(const short8*)&lds[n * TM + (m8 ^ ((n & 7) << 3))];
            int gm = m0 + m8;
            int gb = gm >> sshift, s = gm & smask;
            *(short8*)&CkT[((size_t)gb * N + (n0 + n)) * (size_t)(smask + 1) + s] = v;
        }
    }
}

// ---------------- banded attention (8 waves / 512 threads, QBLK=16) ----------------
__global__ __launch_bounds__(512) void band_attn_mfma(
    const short* __restrict__ qbf, const short* __restrict__ kbf,
    const short* __restrict__ kT, const int* __restrict__ kmul_p,
    float* __restrict__ out, float* __restrict__ attn,
    int S, int H, float scale)
{
    __shared__ float sc[QBLK][SCP];   // scores -> normalized probs (f32)
    __shared__ short pl[QBLK][PPAD];  // probs bf16 for PV A-frags

    // XCD-contiguous tile swizzle (bijective when gridDim.x % 8 == 0).
    int bx = blockIdx.x;
    int tile = bx;
    if ((gridDim.x & 7) == 0) {
        int chunk = gridDim.x >> 3;
        tile = (bx & 7) * chunk + (bx >> 3);
    }

    const int i0  = tile * QBLK;
    const int b   = blockIdx.y;
    const int tid = threadIdx.x;
    const int lane = tid & 63;
    const int w    = tid >> 6;
    const int km   = kmul_p[0];
    const int jbase = max(i0 - (KW - QBLK), 0);   // covers keys [i0-km, i0+QBLK-1]

    const int lr = lane & 15;
    const int lk = (lane >> 4) * 8;
    const int fr = (lane >> 4) * 4;   // frag row base = (lane>>4)*4 + reg

    // ---- scores: D[q][key], waves 0..5 handle keys [16w, 16w+16) ----
    const short* qb = qbf + ((size_t)b * S + i0) * H;
    const short* kb = kbf + ((size_t)b * S + jbase) * H;
    if (w < 6) {
        f32x4 sacc;
        #pragma unroll
        for (int r = 0; r < 4; ++r) sacc[r] = 0.f;
        #pragma unroll
        for (int ks = 0; ks < 16; ++ks) {      // H=512 / 32
            int hoff = ks * 32 + lk;
            short8 qa = *(const short8*)(qb + (size_t)lr * H + hoff);
            short8 kf = *(const short8*)(kb + (size_t)(w * 16 + lr) * H + hoff);
            sacc = __builtin_amdgcn_mfma_f32_16x16x32_bf16(qa, kf, sacc, 0, 0, 0);
        }
        // mask + scale -> sc. key col = lane&15 -> key = 16w + lr.
        int key = w * 16 + lr;
        int kg  = jbase + key;
        #pragma unroll
        for (int r = 0; r < 4; ++r) {
            int q = fr + r;
            int irow = i0 + q;
            bool ok = (kg <= irow) && (kg + km >= irow);
            sc[q][key] = ok ? sacc[r] * scale : -1e30f;
        }
    }
    __syncthreads();

    // ---- softmax: threads 0..255, 16 threads per row, 6 cols each ----
    if (tid < 256) {
        int r = tid >> 4;         // 0..15
        int t = tid & 15;
        float v[6];
        #pragma unroll
        for (int c = 0; c < 6; ++c) v[c] = sc[r][t * 6 + c];
        float mx = -FLT_MAX;
        #pragma unroll
        for (int c = 0; c < 6; ++c) mx = fmaxf(mx, v[c]);
        mx = fmaxf(mx, __shfl_xor(mx, 1, 64));
        mx = fmaxf(mx, __shfl_xor(mx, 2, 64));
        mx = fmaxf(mx, __shfl_xor(mx, 4, 64));
        mx = fmaxf(mx, __shfl_xor(mx, 8, 64));
        float e[6], s = 0.f;
        #pragma unroll
        for (int c = 0; c < 6; ++c) { e[c] = __expf(v[c] - mx); s += e[c]; }
        s += __shfl_xor(s, 1, 64);
        s += __shfl_xor(s, 2, 64);
        s += __shfl_xor(s, 4, 64);
        s += __shfl_xor(s, 8, 64);
        float inv = __frcp_rn(s);
        #pragma unroll
        for (int c = 0; c < 6; ++c) {
            float p = e[c] * inv;
            sc[r][t * 6 + c] = p;
            pl[r][t * 6 + c] = f2bf(p);
        }
    }
    __syncthreads();

    // ---- PV first (loads + MFMA + out stores BEFORE the attn store burst) ----
    short8 pa[3];
    #pragma unroll
    for (int ks = 0; ks < 3; ++ks)
        pa[ks] = *(const short8*)&pl[lr][ks * 32 + lk];

    const short* ktb = kT + (size_t)b * H * S;
    float* obase = out + ((size_t)b * S + i0) * H;
    #pragma unroll
    for (int nf = 0; nf < 4; ++nf) {
        int h = w * 64 + nf * 16 + lr;
        f32x4 oacc;
        #pragma unroll
        for (int r = 0; r < 4; ++r) oacc[r] = 0.f;
        #pragma unroll
        for (int ks = 0; ks < 3; ++ks) {
            short8 kf = *(const short8*)(ktb + (size_t)h * S + jbase + ks * 32 + lk);
            oacc = __builtin_amdgcn_mfma_f32_16x16x32_bf16(pa[ks], kf, oacc, 0, 0, 0);
        }
        #pragma unroll
        for (int r = 0; r < 4; ++r) {
            int q = fr + r;
            __builtin_nontemporal_store(oacc[r], obase + (size_t)q * H + h);
        }
    }

    // ---- dense attn write LAST: band probs, zeros elsewhere (NT stores) ----
    float* abase = attn + ((size_t)b * S + i0) * (size_t)S;
    const int col = tid * 4;   // 512 threads * 4 = 2048 = S exactly
    #pragma unroll 4
    for (int r = 0; r < QBLK; ++r) {
        f32x4 o;
        #pragma unroll
        for (int j = 0; j < 4; ++j) {
            int rel = col + j - jbase;
            o[j] = ((unsigned)rel < (unsigned)KW) ? sc[r][rel] : 0.f;
        }
        __builtin_nontemporal_store(o, (f32x4*)(abase + (size_t)r * S + col));
    }
}

extern "C" void kernel_launch(void* const* d_in, const int* in_sizes, int n_in,
                              void* d_out, int out_size, void* d_ws, size_t ws_size,
                              hipStream_t stream)
{
    const float* x  = (const float*)d_in[0];
    const float* Wk = (const float*)d_in[1];
    const float* bk = (const float*)d_in[2];
    const float* Wq = (const float*)d_in[3];
    const float* bq = (const float*)d_in[4];
    const int*   km = (const int*)d_in[5];

    const int H = in_sizes[2];                               // 512
    const long long BS = (long long)in_sizes[0] / H;         // 8192
    const long long S = ((long long)out_size - (long long)in_sizes[0]) / BS; // 2048
    const int B = (int)(BS / S);
    int sshift = 0;
    while ((1LL << sshift) < S) ++sshift;                    // S is a power of 2

    // ws layout: kT first (tail reads overrun into qbf: finite bf16),
    // then qbf, then kbf.
    short* kT  = (short*)d_ws;                  // [B][H][S]
    short* qbf = kT + (size_t)B * H * S;        // [BS][H]
    short* kbf = qbf + (size_t)BS * H;          // [BS][H]

    dim3 gg((unsigned)(BS / TM), (unsigned)(H / TN), 2);
    gemm_mfma_relu_bias_bf16<<<gg, 256, 0, stream>>>(
        x, Wq, bq, qbf, Wk, bk, kbf, kT, (int)BS, H, H, sshift);

    float* outp  = (float*)d_out;
    float* attnp = outp + (size_t)BS * H;
    const float scale = 1.0f / sqrtf((float)H);

    dim3 ag((unsigned)(S / QBLK), (unsigned)B);
    band_attn_mfma<<<ag, 512, 0, stream>>>(qbf, kbf, kT, km, outp, attnp,
                                           (int)S, H, scale);
}

// Round 8
// 49.541 us; speedup vs baseline: 4.5536x; 1.1342x over previous
//
#include <hip/hip_runtime.h>
#include <hip/hip_bf16.h>
#include <float.h>
#include <math.h>

// B=4, S=2048, H=512, k_mul=64. M=B*S=8192.
// Stage 1: GEMM q/k = relu(x)@W^T + b via bf16 MFMA -> bf16 qbf/kbf + kT.
//          ALSO zero-fills the entire attn output, interleaved into the
//          K-loop (4 f32x4 stores/thread/step) so the 67MB zero drain hides
//          under MFMA compute and background L2->HBM write-back.
// Stage 2: banded attention, QBLK=16 rows/block, KW=96 window, 8 waves.
//          Writes ONLY the band window (3.1MB) + out; zeros elsewhere were
//          pre-filled by stage 1 (stream order guarantees visibility).

typedef __attribute__((ext_vector_type(4))) float f32x4;
typedef __attribute__((ext_vector_type(8))) short short8;
typedef __attribute__((ext_vector_type(4))) short short4v;

#define TM 128
#define TN 128
#define TK 64

#define QBLK 16
#define KW 96      // window; needs k_mul <= KW - QBLK = 80
#define SCP 100    // f32 LDS row stride (pad)
#define PPAD 104   // bf16 LDS row stride

static __device__ __forceinline__ short f2bf(float f) {
    __hip_bfloat16 h = __float2bfloat16(f);  // RNE
    return *reinterpret_cast<short*>(&h);
}

// ---------------- GEMM: C = relu(A) @ W^T + bias, bf16 outputs + attn zerofill ----------------
__global__ __launch_bounds__(256) void gemm_mfma_relu_bias_bf16(
    const float* __restrict__ A,
    const float* __restrict__ Wq, const float* __restrict__ bq, short* __restrict__ Cq,
    const float* __restrict__ Wk, const float* __restrict__ bk, short* __restrict__ Ck,
    short* __restrict__ CkT, float* __restrict__ attnz, long long zPerBlk4,
    int M, int N, int K, int sshift)
{
    const float* W    = blockIdx.z ? Wk : Wq;
    const float* bias = blockIdx.z ? bk : bq;
    short*       C    = blockIdx.z ? Ck : Cq;

    __shared__ __align__(16) short lds[TM * TN];   // 32KB; union: staging + epilogue
    short* As = lds;               // [128][64] swizzled
    short* Bs = lds + TM * TK;

    const int tid  = threadIdx.x;
    const int lane = tid & 63;
    const int wave = tid >> 6;
    const int wr   = (wave >> 1) * 64;
    const int wc   = (wave & 1) * 64;
    const int m0   = blockIdx.x * TM;
    const int n0   = blockIdx.y * TN;

    // attn zero-fill bookkeeping: this block owns f32x4 range
    // [blkLin*zPerBlk4, (blkLin+1)*zPerBlk4), split across K-steps.
    const int blkLin = blockIdx.x + gridDim.x * (blockIdx.y + gridDim.y * blockIdx.z);
    f32x4* zp = (f32x4*)attnz;
    const size_t zbase = (size_t)blkLin * (size_t)zPerBlk4;
    const int nsteps = K / TK;
    const int perStep = (int)(zPerBlk4 / ((long long)nsteps * 256));  // 4 for defaults
    const f32x4 z4 = {0.f, 0.f, 0.f, 0.f};

    const int lr = lane & 15;
    const int lk = (lane >> 4) * 8;

    f32x4 acc[4][4];
    #pragma unroll
    for (int m = 0; m < 4; ++m)
        #pragma unroll
        for (int n = 0; n < 4; ++n)
            #pragma unroll
            for (int r = 0; r < 4; ++r) acc[m][n][r] = 0.f;

    for (int k0 = 0; k0 < K; k0 += TK) {
        #pragma unroll
        for (int i = 0; i < 8; ++i) {
            int f   = tid + (i << 8);
            int row = f >> 4;
            int cq  = (f & 15) << 2;
            int sidx = row * TK + (cq ^ ((row & 7) << 3));
            float4 va = *(const float4*)&A[(size_t)(m0 + row) * K + k0 + cq];
            short4v sa;
            sa.x = f2bf(fmaxf(va.x, 0.f));
            sa.y = f2bf(fmaxf(va.y, 0.f));
            sa.z = f2bf(fmaxf(va.z, 0.f));
            sa.w = f2bf(fmaxf(va.w, 0.f));
            *(short4v*)&As[sidx] = sa;
            float4 vb = *(const float4*)&W[(size_t)(n0 + row) * K + k0 + cq];
            short4v sb;
            sb.x = f2bf(vb.x);
            sb.y = f2bf(vb.y);
            sb.z = f2bf(vb.z);
            sb.w = f2bf(vb.w);
            *(short4v*)&Bs[sidx] = sb;
        }
        __syncthreads();

        #pragma unroll
        for (int kk = 0; kk < 2; ++kk) {
            short8 af[4], bf[4];
            #pragma unroll
            for (int m = 0; m < 4; ++m) {
                int r = wr + m * 16 + lr;
                af[m] = *(const short8*)&As[r * TK + ((kk * 32 + lk) ^ ((r & 7) << 3))];
            }
            #pragma unroll
            for (int n = 0; n < 4; ++n) {
                int r = wc + n * 16 + lr;
                bf[n] = *(const short8*)&Bs[r * TK + ((kk * 32 + lk) ^ ((r & 7) << 3))];
            }
            #pragma unroll
            for (int m = 0; m < 4; ++m)
                #pragma unroll
                for (int n = 0; n < 4; ++n)
                    acc[m][n] = __builtin_amdgcn_mfma_f32_16x16x32_bf16(
                        af[m], bf[n], acc[m][n], 0, 0, 0);
        }

        // interleaved attn zero-fill: 4KB-contiguous bursts per 256 threads;
        // acks at L2, drains to HBM in background under later compute.
        {
            int s = k0 / TK;
            size_t off = zbase + (size_t)s * perStep * 256 + tid;
            for (int j = 0; j < perStep; ++j)
                zp[off + (size_t)j * 256] = z4;
        }
        __syncthreads();
    }

    // ---- epilogue: bias add, bf16, LDS-roundtrip for coalesced writes ----
    float bv[4];
    #pragma unroll
    for (int n = 0; n < 4; ++n) bv[n] = bias[n0 + wc + n * 16 + lr];
    const int cr = (lane >> 4) * 4;

    #pragma unroll
    for (int m = 0; m < 4; ++m)
        #pragma unroll
        for (int n = 0; n < 4; ++n) {
            int col = wc + n * 16 + lr;
            #pragma unroll
            for (int r = 0; r < 4; ++r) {
                int row = wr + m * 16 + cr + r;
                lds[row * TN + (col ^ ((row & 7) << 3))] = f2bf(acc[m][n][r] + bv[n]);
            }
        }
    __syncthreads();
    #pragma unroll
    for (int i = 0; i < 8; ++i) {
        int idx = tid + (i << 8);
        int m = idx >> 4, n8 = (idx & 15) << 3;
        short8 v = *(const short8*)&lds[m * TN + (n8 ^ ((m & 7) << 3))];
        *(short8*)&C[(size_t)(m0 + m) * N + n0 + n8] = v;
    }

    if (blockIdx.z) {   // K: also emit kT[b][h][s]
        __syncthreads();
        #pragma unroll
        for (int m = 0; m < 4; ++m)
            #pragma unroll
            for (int n = 0; n < 4; ++n) {
                int col = wc + n * 16 + lr;
                #pragma unroll
                for (int r = 0; r < 4; ++r) {
                    int row = wr + m * 16 + cr + r;
                    lds[col * TM + (row ^ ((col & 7) << 3))] = f2bf(acc[m][n][r] + bv[n]);
                }
            }
        __syncthreads();
        const int smask = (1 << sshift) - 1;
        #pragma unroll
        for (int i = 0; i < 8; ++i) {
            int idx = tid + (i << 8);
            int n = idx >> 4, m8 = (idx & 15) << 3;
            short8 v = *(const short8*)&lds[n * TM + (m8 ^ ((n & 7) << 3))];
            int gm = m0 + m8;
            int gb = gm >> sshift, s = gm & smask;
            *(short8*)&CkT[((size_t)gb * N + (n0 + n)) * (size_t)(smask + 1) + s] = v;
        }
    }
}

// ---------------- banded attention (8 waves / 512 threads, QBLK=16) ----------------
__global__ __launch_bounds__(512) void band_attn_mfma(
    const short* __restrict__ qbf, const short* __restrict__ kbf,
    const short* __restrict__ kT, const int* __restrict__ kmul_p,
    float* __restrict__ out, float* __restrict__ attn,
    int S, int H, float scale)
{
    __shared__ float sc[QBLK][SCP];   // scores -> normalized probs (f32)
    __shared__ short pl[QBLK][PPAD];  // probs bf16 for PV A-frags

    // XCD-contiguous tile swizzle (bijective when gridDim.x % 8 == 0).
    int bx = blockIdx.x;
    int tile = bx;
    if ((gridDim.x & 7) == 0) {
        int chunk = gridDim.x >> 3;
        tile = (bx & 7) * chunk + (bx >> 3);
    }

    const int i0  = tile * QBLK;
    const int b   = blockIdx.y;
    const int tid = threadIdx.x;
    const int lane = tid & 63;
    const int w    = tid >> 6;
    const int km   = kmul_p[0];
    const int jbase = max(i0 - (KW - QBLK), 0);   // covers keys [i0-km, i0+QBLK-1]

    const int lr = lane & 15;
    const int lk = (lane >> 4) * 8;
    const int fr = (lane >> 4) * 4;   // frag row base = (lane>>4)*4 + reg

    // ---- scores: D[q][key], waves 0..5 handle keys [16w, 16w+16) ----
    const short* qb = qbf + ((size_t)b * S + i0) * H;
    const short* kb = kbf + ((size_t)b * S + jbase) * H;
    if (w < 6) {
        f32x4 sacc;
        #pragma unroll
        for (int r = 0; r < 4; ++r) sacc[r] = 0.f;
        #pragma unroll
        for (int ks = 0; ks < 16; ++ks) {      // H=512 / 32
            int hoff = ks * 32 + lk;
            short8 qa = *(const short8*)(qb + (size_t)lr * H + hoff);
            short8 kf = *(const short8*)(kb + (size_t)(w * 16 + lr) * H + hoff);
            sacc = __builtin_amdgcn_mfma_f32_16x16x32_bf16(qa, kf, sacc, 0, 0, 0);
        }
        // mask + scale -> sc. key col = lane&15 -> key = 16w + lr.
        int key = w * 16 + lr;
        int kg  = jbase + key;
        #pragma unroll
        for (int r = 0; r < 4; ++r) {
            int q = fr + r;
            int irow = i0 + q;
            bool ok = (kg <= irow) && (kg + km >= irow);
            sc[q][key] = ok ? sacc[r] * scale : -1e30f;
        }
    }
    __syncthreads();

    // ---- softmax: threads 0..255, 16 threads per row, 6 cols each ----
    if (tid < 256) {
        int r = tid >> 4;         // 0..15
        int t = tid & 15;
        float v[6];
        #pragma unroll
        for (int c = 0; c < 6; ++c) v[c] = sc[r][t * 6 + c];
        float mx = -FLT_MAX;
        #pragma unroll
        for (int c = 0; c < 6; ++c) mx = fmaxf(mx, v[c]);
        mx = fmaxf(mx, __shfl_xor(mx, 1, 64));
        mx = fmaxf(mx, __shfl_xor(mx, 2, 64));
        mx = fmaxf(mx, __shfl_xor(mx, 4, 64));
        mx = fmaxf(mx, __shfl_xor(mx, 8, 64));
        float e[6], s = 0.f;
        #pragma unroll
        for (int c = 0; c < 6; ++c) { e[c] = __expf(v[c] - mx); s += e[c]; }
        s += __shfl_xor(s, 1, 64);
        s += __shfl_xor(s, 2, 64);
        s += __shfl_xor(s, 4, 64);
        s += __shfl_xor(s, 8, 64);
        float inv = __frcp_rn(s);
        #pragma unroll
        for (int c = 0; c < 6; ++c) {
            float p = e[c] * inv;
            sc[r][t * 6 + c] = p;
            pl[r][t * 6 + c] = f2bf(p);
        }
    }
    __syncthreads();

    // ---- PV (loads + MFMA + out stores) ----
    short8 pa[3];
    #pragma unroll
    for (int ks = 0; ks < 3; ++ks)
        pa[ks] = *(const short8*)&pl[lr][ks * 32 + lk];

    const short* ktb = kT + (size_t)b * H * S;
    float* obase = out + ((size_t)b * S + i0) * H;
    #pragma unroll
    for (int nf = 0; nf < 4; ++nf) {
        int h = w * 64 + nf * 16 + lr;
        f32x4 oacc;
        #pragma unroll
        for (int r = 0; r < 4; ++r) oacc[r] = 0.f;
        #pragma unroll
        for (int ks = 0; ks < 3; ++ks) {
            short8 kf = *(const short8*)(ktb + (size_t)h * S + jbase + ks * 32 + lk);
            oacc = __builtin_amdgcn_mfma_f32_16x16x32_bf16(pa[ks], kf, oacc, 0, 0, 0);
        }
        #pragma unroll
        for (int r = 0; r < 4; ++r) {
            int q = fr + r;
            __builtin_nontemporal_store(oacc[r], obase + (size_t)q * H + h);
        }
    }

    // ---- band-only attn write (zeros pre-filled by GEMM kernel) ----
    // KW/4 = 24 f32x4 per row, QBLK=16 rows -> 384 threads, one f32x4 each.
    if (tid < (KW / 4) * QBLK) {
        int r = tid / (KW / 4);
        int c = tid % (KW / 4);
        f32x4 o;
        #pragma unroll
        for (int j = 0; j < 4; ++j) o[j] = sc[r][c * 4 + j];
        *(f32x4*)(attn + ((size_t)b * S + i0 + r) * (size_t)S + jbase + c * 4) = o;
    }
}

extern "C" void kernel_launch(void* const* d_in, const int* in_sizes, int n_in,
                              void* d_out, int out_size, void* d_ws, size_t ws_size,
                              hipStream_t stream)
{
    const float* x  = (const float*)d_in[0];
    const float* Wk = (const float*)d_in[1];
    const float* bk = (const float*)d_in[2];
    const float* Wq = (const float*)d_in[3];
    const float* bq = (const float*)d_in[4];
    const int*   km = (const int*)d_in[5];

    const int H = in_sizes[2];                               // 512
    const long long BS = (long long)in_sizes[0] / H;         // 8192
    const long long S = ((long long)out_size - (long long)in_sizes[0]) / BS; // 2048
    const int B = (int)(BS / S);
    int sshift = 0;
    while ((1LL << sshift) < S) ++sshift;                    // S is a power of 2

    // ws layout: kT first (tail reads overrun into qbf: finite bf16),
    // then qbf, then kbf.
    short* kT  = (short*)d_ws;                  // [B][H][S]
    short* qbf = kT + (size_t)B * H * S;        // [BS][H]
    short* kbf = qbf + (size_t)BS * H;          // [BS][H]

    float* outp  = (float*)d_out;
    float* attnp = outp + (size_t)BS * H;

    dim3 gg((unsigned)(BS / TM), (unsigned)(H / TN), 2);
    const long long nblk = (long long)gg.x * gg.y * 2;
    const long long zPerBlk4 = ((long long)B * S * S / 4) / nblk;  // 8192 default

    gemm_mfma_relu_bias_bf16<<<gg, 256, 0, stream>>>(
        x, Wq, bq, qbf, Wk, bk, kbf, kT, attnp, zPerBlk4,
        (int)BS, H, H, sshift);

    const float scale = 1.0f / sqrtf((float)H);

    dim3 ag((unsigned)(S / QBLK), (unsigned)B);
    band_attn_mfma<<<ag, 512, 0, stream>>>(qbf, kbf, kT, km, outp, attnp,
                                           (int)S, H, scale);
}